// Round 3
// baseline (2332.787 us; speedup 1.0000x reference)
//
#include <hip/hip_runtime.h>

typedef unsigned short u16;
typedef __attribute__((ext_vector_type(8))) short short8;
typedef __attribute__((ext_vector_type(4))) float f32x4;
typedef __attribute__((ext_vector_type(4))) int int4v;

#define NN 128000
#define EE 512000
#define GB 128
#define EPB 2048   // edges per block in k_edge

__device__ __forceinline__ float u2f(u16 u) {
  union { unsigned u32; float f; } v; v.u32 = ((unsigned)u) << 16; return v.f;
}
__device__ __forceinline__ u16 f2bf(float x) {
  union { float f; unsigned u; } v; v.f = x;
  unsigned r = v.u + 0x7FFF + ((v.u >> 16) & 1);
  return (u16)(r >> 16);
}

// ---- weight transposes: lin_wT[33][256] f32, w1T[78][64] f32, w2T[192][256] f32,
// ---- w3t[k][o][c] bf16 (5x1024x256, from f32 w3[o][c][k])
__global__ void k_transpose(const float* lin_w, const float* w1, const float* w2, const float* w3,
                            float* lin_wT, float* w1T, float* w2T, u16* w3t) {
  int idx = blockIdx.x * 256 + threadIdx.x;
  if (idx < 8448) { int i = idx >> 8, o = idx & 255; lin_wT[idx] = lin_w[o * 33 + i]; return; }
  idx -= 8448;
  if (idx < 4992) { int o = idx & 63, ck = idx >> 6; w1T[idx] = w1[o * 78 + ck]; return; }
  idx -= 4992;
  if (idx < 49152) { int o = idx & 255, ck = idx >> 8; w2T[idx] = w2[o * 192 + ck]; return; }
  idx -= 49152;
  if (idx < 1310720) {
    int c = idx & 255, o = (idx >> 8) & 1023, k = idx >> 18;
    w3t[idx] = f2bf(w3[o * 1280 + c * 5 + k]);
  }
}

// ---- in-degree over col (atomic, sparse targets); graph boundaries from sorted batch
__global__ void k_deg_start(const int* ei, const int* batch, int* deg, int* start) {
  int i = blockIdx.x * 256 + threadIdx.x;
  if (i < EE) atomicAdd(&deg[ei[EE + i]], 1);
  if (i < NN) {
    int b = batch[i];
    if (i == 0) start[0] = 0;
    else { int pb = batch[i - 1]; if (b != pb) start[b] = i; }
    if (i == NN - 1) start[GB] = NN;
  }
}

// ---- xw[n][c] = x[n] . lin_w[c] (bf16 out);  dis[n] = deg>0 ? deg^-0.5 : 0
__global__ void k_xw(const float* x, const float* lin_wT, const int* deg, u16* xw, float* dis) {
  __shared__ float xs[32][34];
  int tid = threadIdx.x, n0 = blockIdx.x * 32;
  int q = tid >> 6, lane = tid & 63;
  for (int n = q; n < 32; n += 4)
    if (lane < 33) xs[n][lane] = x[(n0 + n) * 33 + lane];
  float w[33];
#pragma unroll
  for (int i = 0; i < 33; i++) w[i] = lin_wT[i * 256 + tid];
  __syncthreads();
  for (int n = 0; n < 32; n++) {
    float acc = 0.f;
#pragma unroll
    for (int i = 0; i < 33; i++) acc += w[i] * xs[n][i];
    xw[(size_t)(n0 + n) * 256 + tid] = f2bf(acc);
  }
  if (tid < 32) { int d = deg[n0 + tid]; dis[n0 + tid] = d > 0 ? rsqrtf((float)d) : 0.f; }
}

// ---- LDS-privatized GNN aggregation straight into gsum[c][b]:
// ---- gsum[c][b] += sum over edges e with batch[col_e]==b of dis[row]*dis[col]*xw[row][c]
// ---- grid (E/EPB, 4 channel-groups); block 256 = 4 waves, each wave owns one edge/iter
__global__ void k_edge(const int* ei, const int* batch, const float* dis,
                       const u16* xw, float* gsum) {
  __shared__ float lsum[GB][64];   // [graph][ch-in-group], 32 KB; bank = ch%32 (2-way, free)
  int tid = threadIdx.x;
  int cg = blockIdx.y;             // 0..3
  int e0 = blockIdx.x * EPB;
  for (int i = tid; i < GB * 64; i += 256) ((float*)lsum)[i] = 0.f;
  __syncthreads();
  int wv = tid >> 6, ch = tid & 63;
#pragma unroll 4
  for (int e = e0 + wv; e < e0 + EPB; e += 4) {
    int row = ei[e], col = ei[EE + e];
    float nrm = dis[row] * dis[col];
    int g = batch[col];
    float v = u2f(xw[(size_t)row * 256 + cg * 64 + ch]);
    if (nrm != 0.f) atomicAdd(&lsum[g][ch], nrm * v);
  }
  __syncthreads();
  for (int i = tid; i < GB * 64; i += 256) {
    int g = i >> 6, c = i & 63;
    float v = lsum[g][c];
    if (v != 0.f) atomicAdd(&gsum[(cg * 64 + c) * GB + g], v);
  }
}

// ---- conv1: target[b0+bl][26][1000] -> h1[bl][64][998] f32 (relu)
__global__ void k_conv1(const float* target, const float* w1T, const float* b1, float* h1, int b0) {
  __shared__ float ts[26][132];
  __shared__ float wls[78 * 64];
  int tid = threadIdx.x, lt = blockIdx.x, bl = blockIdx.y;
  int bg = b0 + bl;
  int l0 = lt * 128;
  int q = tid >> 6, lane = tid & 63;
  for (int c = q; c < 26; c += 4)
    for (int i = lane; i < 130; i += 64)
      ts[c][i] = target[(bg * 26 + c) * 1000 + min(l0 + i, 999)];
  for (int i = tid; i < 4992; i += 256) wls[i] = w1T[i];
  __syncthreads();
  int l = tid & 127, oh = tid >> 7;
  float acc[32];
#pragma unroll
  for (int j = 0; j < 32; j++) acc[j] = 0.f;
  for (int c = 0; c < 26; c++) {
#pragma unroll
    for (int k = 0; k < 3; k++) {
      float tv = ts[c][l + k];
      const float* wp = &wls[(c * 3 + k) * 64 + oh * 32];
#pragma unroll
      for (int j = 0; j < 32; j++) acc[j] += tv * wp[j];
    }
  }
  int lg = l0 + l;
  if (lg < 998) {
#pragma unroll
    for (int j = 0; j < 32; j++) {
      int o = oh * 32 + j;
      h1[((size_t)bl * 64 + o) * 998 + lg] = fmaxf(acc[j] + b1[o], 0.f);
    }
  }
}

// ---- conv2: h1[bl][64][998] -> h2T[bl][996][256] bf16 channel-last (relu)
__global__ void k_conv2(const float* h1, const float* w2T, const float* b2, u16* h2T) {
  __shared__ float h1s[64][132];
  int tid = threadIdx.x, lt = blockIdx.x, bl = blockIdx.y;
  int l0 = lt * 128;
  int q = tid >> 6, lane = tid & 63;
  for (int c = q; c < 64; c += 4)
    for (int i = lane; i < 130; i += 64)
      h1s[c][i] = h1[((size_t)bl * 64 + c) * 998 + min(l0 + i, 997)];
  __syncthreads();
  int o = tid;
  float bias = b2[o];
  for (int lc = 0; lc < 8; lc++) {
    float acc[16];
#pragma unroll
    for (int r = 0; r < 16; r++) acc[r] = 0.f;
    for (int c = 0; c < 64; c++) {
      float win[20];
      const float4* wp = (const float4*)&h1s[c][lc * 16];
#pragma unroll
      for (int t = 0; t < 5; t++) {
        float4 v = wp[t];
        win[t * 4 + 0] = v.x; win[t * 4 + 1] = v.y; win[t * 4 + 2] = v.z; win[t * 4 + 3] = v.w;
      }
#pragma unroll
      for (int k = 0; k < 3; k++) {
        float w = w2T[(c * 3 + k) * 256 + o];
#pragma unroll
        for (int r = 0; r < 16; r++) acc[r] += win[r + k] * w;
      }
    }
#pragma unroll
    for (int r = 0; r < 16; r++) {
      int lg = l0 + lc * 16 + r;
      if (lg < 996) h2T[((size_t)bl * 996 + lg) * 256 + o] = f2bf(fmaxf(acc[r] + bias, 0.f));
    }
  }
}

// ---- conv3 as 5 shifted GEMMs via MFMA, fused max-pool+bias+relu -> pooledT[o][b0+bl] f32
__global__ void k_conv3(const u16* h2T, const u16* w3t, const float* b3, float* pooledT, int b0) {
  __shared__ u16 als[128 * 40];      // A tile [m=l][t=c], row stride 40 (pad 8) bf16
  __shared__ u16 bls[128 * 40];      // B tile [n=o][t=c]
  __shared__ float mbuf[2][128];
  int tid = threadIdx.x;
  int ot = blockIdx.x, bl = blockIdx.y;
  int o0 = ot * 128;
  int lane = tid & 63, wid = tid >> 6;
  int wm = wid >> 1, wn = wid & 1;
  int quad = lane >> 4, l16 = lane & 15;
  float omax[4];
#pragma unroll
  for (int j = 0; j < 4; j++) omax[j] = -3.0e38f;
  const f32x4 zero = {0.f, 0.f, 0.f, 0.f};
  for (int lt = 0; lt < 8; lt++) {
    int l0 = lt * 128;
    f32x4 acc[4][4];
#pragma unroll
    for (int i = 0; i < 4; i++)
#pragma unroll
      for (int j = 0; j < 4; j++) acc[i][j] = zero;
    for (int k = 0; k < 5; k++) {
      for (int cb = 0; cb < 8; cb++) {
        int c0 = cb * 32;
#pragma unroll
        for (int rep = 0; rep < 2; rep++) {
          int cid = tid + 256 * rep;           // 0..511
          int m = cid >> 2, ch = cid & 3;
          int rowA = min(l0 + m + k, 995);
          *(int4v*)(als + m * 40 + ch * 8) =
              *(const int4v*)(h2T + ((size_t)bl * 996 + rowA) * 256 + c0 + ch * 8);
          *(int4v*)(bls + m * 40 + ch * 8) =
              *(const int4v*)(w3t + ((size_t)(k * 1024 + o0 + m)) * 256 + c0 + ch * 8);
        }
        __syncthreads();
        short8 af[4], bfr[4];
#pragma unroll
        for (int i = 0; i < 4; i++)
          af[i] = *(const short8*)(als + (wm * 64 + i * 16 + l16) * 40 + quad * 8);
#pragma unroll
        for (int j = 0; j < 4; j++)
          bfr[j] = *(const short8*)(bls + (wn * 64 + j * 16 + l16) * 40 + quad * 8);
#pragma unroll
        for (int i = 0; i < 4; i++)
#pragma unroll
          for (int j = 0; j < 4; j++)
            acc[i][j] = __builtin_amdgcn_mfma_f32_16x16x32_bf16(af[i], bfr[j], acc[i][j], 0, 0, 0);
        __syncthreads();
      }
    }
    // fold this l-tile into running per-o max (mask invalid rows l>=992)
#pragma unroll
    for (int i = 0; i < 4; i++) {
#pragma unroll
      for (int r = 0; r < 4; r++) {
        int lg = l0 + wm * 64 + i * 16 + quad * 4 + r;
        if (lg < 992) {
#pragma unroll
          for (int j = 0; j < 4; j++) omax[j] = fmaxf(omax[j], acc[i][j][r]);
        }
      }
    }
  }
#pragma unroll
  for (int j = 0; j < 4; j++) {
    omax[j] = fmaxf(omax[j], __shfl_xor(omax[j], 16, 64));
    omax[j] = fmaxf(omax[j], __shfl_xor(omax[j], 32, 64));
  }
  if (quad == 0) {
#pragma unroll
    for (int j = 0; j < 4; j++) mbuf[wm][wn * 64 + j * 16 + l16] = omax[j];
  }
  __syncthreads();
  if (tid < 128) {
    float v = fmaxf(mbuf[0][tid], mbuf[1][tid]);
    v += b3[o0 + tid];
    pooledT[(size_t)(o0 + tid) * 128 + b0 + bl] = fmaxf(v, 0.f);
  }
}

// ---- z0T[r][b]: rows 0..255 = drug (gsum/cnt + lin_b), rows 256..1023 = tgtT
__global__ void k_z0(const float* gsum, const int* start, const float* lin_b, const float* tgtT,
                     float* z0T) {
  int idx = blockIdx.x * 256 + threadIdx.x;   // < 131072
  int r = idx >> 7, bb = idx & 127;
  float v;
  if (r < 256) {
    float c = (float)(start[bb + 1] - start[bb]);   // every graph non-empty
    v = gsum[idx] / c + lin_b[r];
  } else {
    v = tgtT[(r - 256) * 128 + bb];
  }
  z0T[idx] = v;
}

// ---- generic fc layer on transposed activations: outT[o][b] = act(W[o].zT[:,b] + bias)
__global__ void k_fc(const float* zT, const float* W, const float* bias, float* outT,
                     int K, int O, int relu, float* final_out) {
  __shared__ float wls[2][1024];
  int tid = threadIdx.x;
  int o0 = blockIdx.x * 2;
  for (int idx = tid; idx < 2 * K; idx += 256) {
    int oo = idx >= K ? 1 : 0;
    int i = idx - oo * K;
    if (o0 + oo < O) wls[oo][i] = W[(size_t)(o0 + oo) * K + i];
  }
  __syncthreads();
  int osub = tid >> 7, bb = tid & 127;
  int o = o0 + osub;
  if (o >= O) return;
  float acc = 0.f;
#pragma unroll 8
  for (int i = 0; i < K; i++) acc += wls[osub][i] * zT[i * 128 + bb];
  acc += bias[o];
  if (relu) acc = fmaxf(acc, 0.f);
  if (final_out) {
    if (o == 0) final_out[bb] = acc;
  } else {
    outT[(size_t)o * 128 + bb] = acc;
  }
}

extern "C" void kernel_launch(void* const* d_in, const int* in_sizes, int n_in,
                              void* d_out, int out_size, void* d_ws, size_t ws_size,
                              hipStream_t stream) {
  const float* x      = (const float*)d_in[0];
  const int*   ei     = (const int*)d_in[1];
  const int*   batch  = (const int*)d_in[2];
  const float* target = (const float*)d_in[3];
  const float* lin_w  = (const float*)d_in[4];
  const float* lin_b  = (const float*)d_in[5];
  const float* w1     = (const float*)d_in[6];
  const float* b1     = (const float*)d_in[7];
  const float* w2     = (const float*)d_in[8];
  const float* b2     = (const float*)d_in[9];
  const float* w3     = (const float*)d_in[10];
  const float* b3     = (const float*)d_in[11];
  const float* fcw    = (const float*)d_in[12];
  const float* fcb    = (const float*)d_in[13];
  const float* m1w = (const float*)d_in[14]; const float* m1b = (const float*)d_in[15];
  const float* m2w = (const float*)d_in[16]; const float* m2b = (const float*)d_in[17];
  const float* m3w = (const float*)d_in[18]; const float* m3b = (const float*)d_in[19];
  const float* m4w = (const float*)d_in[20]; const float* m4b = (const float*)d_in[21];

  char* ws = (char*)d_ws;
  size_t ofs = 0;
  auto alloc = [&](size_t bytes) -> void* {
    void* p = ws + ofs;
    ofs = (ofs + bytes + 255) & ~(size_t)255;
    return p;
  };
  // ---- persistent (small) region ----
  int*   deg    = (int*)alloc((size_t)NN * 4);
  float* dis    = (float*)alloc((size_t)NN * 4);
  int*   start  = (int*)alloc((size_t)(GB + 1) * 4);
  float* gsum   = (float*)alloc((size_t)256 * 128 * 4);
  float* lin_wT = (float*)alloc((size_t)33 * 256 * 4);
  float* w1T    = (float*)alloc((size_t)78 * 64 * 4);
  float* w2T    = (float*)alloc((size_t)192 * 256 * 4);
  u16*   w3t    = (u16*)alloc((size_t)5 * 1024 * 256 * 2);
  float* pooledT= (float*)alloc((size_t)1024 * 128 * 4);
  float* tgtT   = (float*)alloc((size_t)768 * 128 * 4);
  float* z0T    = (float*)alloc((size_t)1024 * 128 * 4);
  float* z1T    = (float*)alloc((size_t)1024 * 128 * 4);
  float* z2T    = (float*)alloc((size_t)1024 * 128 * 4);
  float* z3T    = (float*)alloc((size_t)512 * 128 * 4);
  size_t F_end = ofs;

  // ---- dynamic region: xw (GNN phase) aliased by h1+h2T (CNN phase) ----
  u16* xw = (u16*)(ws + F_end);                     // NN*256*2 = 65.5 MB
  // CNN batch-chunk size: constant given ws_size, so identical work every call
  int CB = 64;
  {
    size_t need128 = (size_t)128 * 64 * 998 * 4 + (size_t)128 * 996 * 256 * 2 + 512;
    if (ws_size >= F_end + need128) CB = 128;
  }
  float* h1  = (float*)(ws + F_end);                // CB*64*998*4  (multiple of 256)
  u16*   h2T = (u16*)(ws + F_end + (size_t)CB * 64 * 998 * 4);   // CB*996*256*2

  hipMemsetAsync(deg, 0, (size_t)NN * 4, stream);
  hipMemsetAsync(gsum, 0, (size_t)256 * 128 * 4, stream);

  // ---- GNN phase ----
  k_transpose<<<5365, 256, 0, stream>>>(lin_w, w1, w2, w3, lin_wT, w1T, w2T, w3t);
  k_deg_start<<<2000, 256, 0, stream>>>(ei, batch, deg, start);
  k_xw<<<4000, 256, 0, stream>>>(x, lin_wT, deg, xw, dis);
  k_edge<<<dim3(EE / EPB, 4), 256, 0, stream>>>(ei, batch, dis, xw, gsum);

  // ---- CNN phase (aliases xw region; xw is dead after k_edge) ----
  for (int b0 = 0; b0 < GB; b0 += CB) {
    k_conv1<<<dim3(8, CB), 256, 0, stream>>>(target, w1T, b1, h1, b0);
    k_conv2<<<dim3(8, CB), 256, 0, stream>>>(h1, w2T, b2, h2T);
    k_conv3<<<dim3(8, CB), 256, 0, stream>>>(h2T, w3t, b3, pooledT, b0);
  }

  // ---- head ----
  k_fc<<<384, 256, 0, stream>>>(pooledT, fcw, fcb, tgtT, 1024, 768, 1, nullptr);
  k_z0<<<512, 256, 0, stream>>>(gsum, start, lin_b, tgtT, z0T);
  k_fc<<<512, 256, 0, stream>>>(z0T, m1w, m1b, z1T, 1024, 1024, 1, nullptr);
  k_fc<<<512, 256, 0, stream>>>(z1T, m2w, m2b, z2T, 1024, 1024, 1, nullptr);
  k_fc<<<256, 256, 0, stream>>>(z2T, m3w, m3b, z3T, 1024, 512, 1, nullptr);
  k_fc<<<1, 256, 0, stream>>>(z3T, m4w, m4b, nullptr, 512, 1, 0, (float*)d_out);
}

// Round 4
// 1231.148 us; speedup vs baseline: 1.8948x; 1.8948x over previous
//
#include <hip/hip_runtime.h>

typedef unsigned short u16;
typedef __attribute__((ext_vector_type(8))) short short8;
typedef __attribute__((ext_vector_type(4))) float f32x4;

#define NN 128000
#define EE 512000
#define GB 128

#define GLDS16(g, l)                                                     \
  __builtin_amdgcn_global_load_lds(                                      \
      (const __attribute__((address_space(1))) unsigned int*)(g),        \
      (__attribute__((address_space(3))) unsigned int*)(l), 16, 0, 0)

__device__ __forceinline__ float u2f(u16 u) {
  union { unsigned u32; float f; } v; v.u32 = ((unsigned)u) << 16; return v.f;
}
__device__ __forceinline__ u16 f2bf(float x) {
  union { float f; unsigned u; } v; v.f = x;
  unsigned r = v.u + 0x7FFF + ((v.u >> 16) & 1);
  return (u16)(r >> 16);
}

// ---- weight transposes: lin_wT[33][256] f32, w1T[78][64] f32, w2T[192][256] f32,
// ---- w3t[k][o][c] bf16 (5x1024x256, from f32 w3[o][c][k])
__global__ void k_transpose(const float* lin_w, const float* w1, const float* w2, const float* w3,
                            float* lin_wT, float* w1T, float* w2T, u16* w3t) {
  int idx = blockIdx.x * 256 + threadIdx.x;
  if (idx < 8448) { int i = idx >> 8, o = idx & 255; lin_wT[idx] = lin_w[o * 33 + i]; return; }
  idx -= 8448;
  if (idx < 4992) { int o = idx & 63, ck = idx >> 6; w1T[idx] = w1[o * 78 + ck]; return; }
  idx -= 4992;
  if (idx < 49152) { int o = idx & 255, ck = idx >> 8; w2T[idx] = w2[o * 192 + ck]; return; }
  idx -= 49152;
  if (idx < 1310720) {
    int c = idx & 255, o = (idx >> 8) & 1023, k = idx >> 18;
    w3t[idx] = f2bf(w3[o * 1280 + c * 5 + k]);
  }
}

// ---- in-degree over col; per-graph edge histogram (LDS-privatized); graph boundaries
// ---- grid 500 x 256: 4 edges + 1 node per thread
__global__ void k_deg_start(const int* ei, const int* batch, int* deg, int* start, int* hist) {
  __shared__ int lh[GB];
  int tid = threadIdx.x, blk = blockIdx.x;
  if (tid < GB) lh[tid] = 0;
  __syncthreads();
  int e0 = blk * 1024;
#pragma unroll
  for (int t = 0; t < 4; t++) {
    int e = e0 + t * 256 + tid;
    int col = ei[EE + e];
    atomicAdd(&deg[col], 1);
    atomicAdd(&lh[batch[col]], 1);
  }
  int i = blk * 256 + tid;
  int b = batch[i];
  if (i == 0) start[0] = 0;
  else if (b != batch[i - 1]) start[b] = i;
  if (i == NN - 1) start[GB] = NN;
  __syncthreads();
  if (tid < GB && lh[tid]) atomicAdd(&hist[tid * 16], lh[tid]);
}

// ---- exclusive prefix over 128 bins; init padded cursors. 1 block x 128 threads
__global__ void k_prefix(const int* hist, int* off, int* cursor) {
  __shared__ int h[GB];
  int tid = threadIdx.x;
  h[tid] = hist[tid * 16];
  __syncthreads();
  int s = 0;
  for (int j = 0; j < tid; j++) s += h[j];
  off[tid] = s;
  cursor[tid * 16] = s;
  if (tid == GB - 1) off[GB] = s + h[GB - 1];
}

// ---- xw[n][c] = x[n] . lin_w[c] (bf16 out);  dis[n] = deg>0 ? deg^-0.5 : 0
__global__ void k_xw(const float* x, const float* lin_wT, const int* deg, u16* xw, float* dis) {
  __shared__ float xs[32][34];
  int tid = threadIdx.x, n0 = blockIdx.x * 32;
  int q = tid >> 6, lane = tid & 63;
  for (int n = q; n < 32; n += 4)
    if (lane < 33) xs[n][lane] = x[(n0 + n) * 33 + lane];
  float w[33];
#pragma unroll
  for (int i = 0; i < 33; i++) w[i] = lin_wT[i * 256 + tid];
  __syncthreads();
  for (int n = 0; n < 32; n++) {
    float acc = 0.f;
#pragma unroll
    for (int i = 0; i < 33; i++) acc += w[i] * xs[n][i];
    xw[(size_t)(n0 + n) * 256 + tid] = f2bf(acc);
  }
  if (tid < 32) { int d = deg[n0 + tid]; dis[n0 + tid] = d > 0 ? rsqrtf((float)d) : 0.f; }
}

// ---- bucket edges by graph of col: bucket[slot] = (row, nrm). grid 500 x 256, 4 edges/thread
__global__ void k_scatter(const int* ei, const int* batch, const float* dis,
                          int* cursor, uint2* bucket) {
  __shared__ int lh[GB];
  __shared__ int lbase[GB];
  int tid = threadIdx.x, blk = blockIdx.x;
  if (tid < GB) lh[tid] = 0;
  __syncthreads();
  int e0 = blk * 1024;
  int row[4], g[4], rk[4]; float nrm[4];
#pragma unroll
  for (int t = 0; t < 4; t++) {
    int e = e0 + t * 256 + tid;
    int r = ei[e], c = ei[EE + e];
    row[t] = r;
    g[t] = batch[c];
    nrm[t] = dis[r] * dis[c];
    rk[t] = atomicAdd(&lh[g[t]], 1);
  }
  __syncthreads();
  if (tid < GB && lh[tid]) lbase[tid] = atomicAdd(&cursor[tid * 16], lh[tid]);
  __syncthreads();
#pragma unroll
  for (int t = 0; t < 4; t++) {
    uint2 v; v.x = (unsigned)row[t]; v.y = __float_as_uint(nrm[t]);
    bucket[lbase[g[t]] + rk[t]] = v;
  }
}

// ---- per-graph gather-accumulate: wave = one edge, lane = 4 channels, regs only.
// ---- grid (8 splits, 128 graphs) x 256
__global__ void k_gather(const uint2* bucket, const int* off, const u16* xw, float* gsum) {
  __shared__ float red[4][256];
  int tid = threadIdx.x;
  int s = blockIdx.x, g = blockIdx.y;
  int lo = off[g], hi = off[g + 1];
  int cnt = hi - lo;
  int per = (cnt + 7) >> 3;
  int b0 = lo + s * per, b1 = min(b0 + per, hi);
  int lane = tid & 63, wid = tid >> 6;
  f32x4 acc = {0.f, 0.f, 0.f, 0.f};
  const u16* xbase = xw + lane * 4;
#pragma unroll 4
  for (int e = b0 + wid; e < b1; e += 4) {
    uint2 be = bucket[e];
    float nrm = __uint_as_float(be.y);
    ushort4 v = *(const ushort4*)(xbase + (size_t)be.x * 256);
    acc.x = fmaf(nrm, u2f(v.x), acc.x);
    acc.y = fmaf(nrm, u2f(v.y), acc.y);
    acc.z = fmaf(nrm, u2f(v.z), acc.z);
    acc.w = fmaf(nrm, u2f(v.w), acc.w);
  }
  *(f32x4*)&red[wid][lane * 4] = acc;
  __syncthreads();
  float v = red[0][tid] + red[1][tid] + red[2][tid] + red[3][tid];
  if (v != 0.f) atomicAdd(&gsum[tid * 128 + g], v);
}

// ---- conv1: target[b0+bl][26][1000] -> h1[bl][64][998] f32 (relu)
__global__ void k_conv1(const float* target, const float* w1T, const float* b1, float* h1, int b0) {
  __shared__ float ts[26][132];
  __shared__ float wls[78 * 64];
  int tid = threadIdx.x, lt = blockIdx.x, bl = blockIdx.y;
  int bg = b0 + bl;
  int l0 = lt * 128;
  int q = tid >> 6, lane = tid & 63;
  for (int c = q; c < 26; c += 4)
    for (int i = lane; i < 130; i += 64)
      ts[c][i] = target[(bg * 26 + c) * 1000 + min(l0 + i, 999)];
  for (int i = tid; i < 4992; i += 256) wls[i] = w1T[i];
  __syncthreads();
  int l = tid & 127, oh = tid >> 7;
  float acc[32];
#pragma unroll
  for (int j = 0; j < 32; j++) acc[j] = 0.f;
  for (int c = 0; c < 26; c++) {
#pragma unroll
    for (int k = 0; k < 3; k++) {
      float tv = ts[c][l + k];
      const float* wp = &wls[(c * 3 + k) * 64 + oh * 32];
#pragma unroll
      for (int j = 0; j < 32; j++) acc[j] += tv * wp[j];
    }
  }
  int lg = l0 + l;
  if (lg < 998) {
#pragma unroll
    for (int j = 0; j < 32; j++) {
      int o = oh * 32 + j;
      h1[((size_t)bl * 64 + o) * 998 + lg] = fmaxf(acc[j] + b1[o], 0.f);
    }
  }
}

// ---- conv2: h1[bl][64][998] -> h2T[bl][996][256] bf16 channel-last (relu)
__global__ void k_conv2(const float* h1, const float* w2T, const float* b2, u16* h2T) {
  __shared__ float h1s[64][132];
  int tid = threadIdx.x, lt = blockIdx.x, bl = blockIdx.y;
  int l0 = lt * 128;
  int q = tid >> 6, lane = tid & 63;
  for (int c = q; c < 64; c += 4)
    for (int i = lane; i < 130; i += 64)
      h1s[c][i] = h1[((size_t)bl * 64 + c) * 998 + min(l0 + i, 997)];
  __syncthreads();
  int o = tid;
  float bias = b2[o];
  for (int lc = 0; lc < 8; lc++) {
    float acc[16];
#pragma unroll
    for (int r = 0; r < 16; r++) acc[r] = 0.f;
    for (int c = 0; c < 64; c++) {
      float win[20];
      const float4* wp = (const float4*)&h1s[c][lc * 16];
#pragma unroll
      for (int t = 0; t < 5; t++) {
        float4 v = wp[t];
        win[t * 4 + 0] = v.x; win[t * 4 + 1] = v.y; win[t * 4 + 2] = v.z; win[t * 4 + 3] = v.w;
      }
#pragma unroll
      for (int k = 0; k < 3; k++) {
        float w = w2T[(c * 3 + k) * 256 + o];
#pragma unroll
        for (int r = 0; r < 16; r++) acc[r] += win[r + k] * w;
      }
    }
#pragma unroll
    for (int r = 0; r < 16; r++) {
      int lg = l0 + lc * 16 + r;
      if (lg < 996) h2T[((size_t)bl * 996 + lg) * 256 + o] = f2bf(fmaxf(acc[r] + bias, 0.f));
    }
  }
}

// ---- conv3 as 5 shifted GEMMs via MFMA, global_load_lds(16B) staging, unpadded tiles,
// ---- fused max-pool+bias+relu -> pooledT[o][b0+bl] f32
__global__ void k_conv3(const u16* h2T, const u16* w3t, const float* b3, float* pooledT, int b0) {
  __shared__ u16 als[128 * 32];      // A tile [m=l][c], row 64 B, unpadded (glds order)
  __shared__ u16 bls[128 * 32];      // B tile [n=o][c]
  __shared__ float mbuf[2][128];
  int tid = threadIdx.x;
  int ot = blockIdx.x, bl = blockIdx.y;
  int o0 = ot * 128;
  int lane = tid & 63, wid = tid >> 6;
  int wm = wid >> 1, wn = wid & 1;
  int quad = lane >> 4, l16 = lane & 15;
  float omax[4];
#pragma unroll
  for (int j = 0; j < 4; j++) omax[j] = -3.0e38f;
  const f32x4 zero = {0.f, 0.f, 0.f, 0.f};
  for (int lt = 0; lt < 8; lt++) {
    int l0 = lt * 128;
    f32x4 acc[4][4];
#pragma unroll
    for (int i = 0; i < 4; i++)
#pragma unroll
      for (int j = 0; j < 4; j++) acc[i][j] = zero;
    for (int k = 0; k < 5; k++) {
      for (int cb = 0; cb < 8; cb++) {
        int c0 = cb * 32;
        // stage: 512 16B-chunks each for A and B; chunk cid -> row=cid>>2, ck=cid&3;
        // LDS dest = wave-uniform base + lane*16 (glds semantics)
#pragma unroll
        for (int t = 0; t < 2; t++) {
          int cid = t * 256 + wid * 64 + lane;
          int row = cid >> 2, ck = cid & 3;
          const u16* gA = h2T + ((size_t)bl * 996 + min(l0 + row + k, 995)) * 256 + c0 + ck * 8;
          const u16* gB = w3t + ((size_t)(k * 1024 + o0 + row)) * 256 + c0 + ck * 8;
          GLDS16(gA, als + (t * 256 + wid * 64) * 8);
          GLDS16(gB, bls + (t * 256 + wid * 64) * 8);
        }
        __syncthreads();
        short8 af[4], bfr[4];
#pragma unroll
        for (int i = 0; i < 4; i++)
          af[i] = *(const short8*)(als + (wm * 64 + i * 16 + l16) * 32 + quad * 8);
#pragma unroll
        for (int j = 0; j < 4; j++)
          bfr[j] = *(const short8*)(bls + (wn * 64 + j * 16 + l16) * 32 + quad * 8);
#pragma unroll
        for (int i = 0; i < 4; i++)
#pragma unroll
          for (int j = 0; j < 4; j++)
            acc[i][j] = __builtin_amdgcn_mfma_f32_16x16x32_bf16(af[i], bfr[j], acc[i][j], 0, 0, 0);
        __syncthreads();
      }
    }
    // fold this l-tile into running per-o max (mask invalid rows l>=992)
#pragma unroll
    for (int i = 0; i < 4; i++) {
#pragma unroll
      for (int r = 0; r < 4; r++) {
        int lg = l0 + wm * 64 + i * 16 + quad * 4 + r;
        if (lg < 992) {
#pragma unroll
          for (int j = 0; j < 4; j++) omax[j] = fmaxf(omax[j], acc[i][j][r]);
        }
      }
    }
  }
#pragma unroll
  for (int j = 0; j < 4; j++) {
    omax[j] = fmaxf(omax[j], __shfl_xor(omax[j], 16, 64));
    omax[j] = fmaxf(omax[j], __shfl_xor(omax[j], 32, 64));
  }
  if (quad == 0) {
#pragma unroll
    for (int j = 0; j < 4; j++) mbuf[wm][wn * 64 + j * 16 + l16] = omax[j];
  }
  __syncthreads();
  if (tid < 128) {
    float v = fmaxf(mbuf[0][tid], mbuf[1][tid]);
    v += b3[o0 + tid];
    pooledT[(size_t)(o0 + tid) * 128 + b0 + bl] = fmaxf(v, 0.f);
  }
}

// ---- z0T[r][b]: rows 0..255 = drug (gsum/cnt + lin_b), rows 256..1023 = tgtT
__global__ void k_z0(const float* gsum, const int* start, const float* lin_b, const float* tgtT,
                     float* z0T) {
  int idx = blockIdx.x * 256 + threadIdx.x;   // < 131072
  int r = idx >> 7, bb = idx & 127;
  float v;
  if (r < 256) {
    float c = (float)(start[bb + 1] - start[bb]);   // every graph non-empty
    v = gsum[idx] / c + lin_b[r];
  } else {
    v = tgtT[(r - 256) * 128 + bb];
  }
  z0T[idx] = v;
}

// ---- generic fc layer on transposed activations: outT[o][b] = act(W[o].zT[:,b] + bias)
__global__ void k_fc(const float* zT, const float* W, const float* bias, float* outT,
                     int K, int O, int relu, float* final_out) {
  __shared__ float wls[2][1024];
  int tid = threadIdx.x;
  int o0 = blockIdx.x * 2;
  for (int idx = tid; idx < 2 * K; idx += 256) {
    int oo = idx >= K ? 1 : 0;
    int i = idx - oo * K;
    if (o0 + oo < O) wls[oo][i] = W[(size_t)(o0 + oo) * K + i];
  }
  __syncthreads();
  int osub = tid >> 7, bb = tid & 127;
  int o = o0 + osub;
  if (o >= O) return;
  float acc = 0.f;
#pragma unroll 8
  for (int i = 0; i < K; i++) acc += wls[osub][i] * zT[i * 128 + bb];
  acc += bias[o];
  if (relu) acc = fmaxf(acc, 0.f);
  if (final_out) {
    if (o == 0) final_out[bb] = acc;
  } else {
    outT[(size_t)o * 128 + bb] = acc;
  }
}

extern "C" void kernel_launch(void* const* d_in, const int* in_sizes, int n_in,
                              void* d_out, int out_size, void* d_ws, size_t ws_size,
                              hipStream_t stream) {
  const float* x      = (const float*)d_in[0];
  const int*   ei     = (const int*)d_in[1];
  const int*   batch  = (const int*)d_in[2];
  const float* target = (const float*)d_in[3];
  const float* lin_w  = (const float*)d_in[4];
  const float* lin_b  = (const float*)d_in[5];
  const float* w1     = (const float*)d_in[6];
  const float* b1     = (const float*)d_in[7];
  const float* w2     = (const float*)d_in[8];
  const float* b2     = (const float*)d_in[9];
  const float* w3     = (const float*)d_in[10];
  const float* b3     = (const float*)d_in[11];
  const float* fcw    = (const float*)d_in[12];
  const float* fcb    = (const float*)d_in[13];
  const float* m1w = (const float*)d_in[14]; const float* m1b = (const float*)d_in[15];
  const float* m2w = (const float*)d_in[16]; const float* m2b = (const float*)d_in[17];
  const float* m3w = (const float*)d_in[18]; const float* m3b = (const float*)d_in[19];
  const float* m4w = (const float*)d_in[20]; const float* m4b = (const float*)d_in[21];

  char* ws = (char*)d_ws;
  size_t ofs = 0;
  auto alloc = [&](size_t bytes) -> void* {
    void* p = ws + ofs;
    ofs = (ofs + bytes + 255) & ~(size_t)255;
    return p;
  };
  // ---- persistent (small) region ----
  int*   deg    = (int*)alloc((size_t)NN * 4);
  float* dis    = (float*)alloc((size_t)NN * 4);
  int*   start  = (int*)alloc((size_t)(GB + 1) * 4);
  int*   hist   = (int*)alloc((size_t)GB * 16 * 4);   // padded: one cache line per bin
  int*   off    = (int*)alloc((size_t)(GB + 1) * 4);
  int*   cursor = (int*)alloc((size_t)GB * 16 * 4);   // padded
  uint2* bucket = (uint2*)alloc((size_t)EE * 8);
  float* gsum   = (float*)alloc((size_t)256 * 128 * 4);
  float* lin_wT = (float*)alloc((size_t)33 * 256 * 4);
  float* w1T    = (float*)alloc((size_t)78 * 64 * 4);
  float* w2T    = (float*)alloc((size_t)192 * 256 * 4);
  u16*   w3t    = (u16*)alloc((size_t)5 * 1024 * 256 * 2);
  float* pooledT= (float*)alloc((size_t)1024 * 128 * 4);
  float* tgtT   = (float*)alloc((size_t)768 * 128 * 4);
  float* z0T    = (float*)alloc((size_t)1024 * 128 * 4);
  float* z1T    = (float*)alloc((size_t)1024 * 128 * 4);
  float* z2T    = (float*)alloc((size_t)1024 * 128 * 4);
  float* z3T    = (float*)alloc((size_t)512 * 128 * 4);
  size_t F_end = ofs;

  // ---- dynamic region: xw (GNN phase) aliased by h1+h2T (CNN phase) ----
  u16* xw = (u16*)(ws + F_end);                     // NN*256*2 = 65.5 MB
  int CB = 64;
  {
    size_t need128 = (size_t)128 * 64 * 998 * 4 + (size_t)128 * 996 * 256 * 2 + 512;
    if (ws_size >= F_end + need128) CB = 128;
  }
  float* h1  = (float*)(ws + F_end);                // CB*64*998*4  (multiple of 256)
  u16*   h2T = (u16*)(ws + F_end + (size_t)CB * 64 * 998 * 4);   // CB*996*256*2

  hipMemsetAsync(deg, 0, (size_t)NN * 4, stream);
  hipMemsetAsync(hist, 0, (size_t)GB * 16 * 4, stream);
  hipMemsetAsync(gsum, 0, (size_t)256 * 128 * 4, stream);

  // ---- GNN phase ----
  k_transpose<<<5365, 256, 0, stream>>>(lin_w, w1, w2, w3, lin_wT, w1T, w2T, w3t);
  k_deg_start<<<500, 256, 0, stream>>>(ei, batch, deg, start, hist);
  k_prefix<<<1, 128, 0, stream>>>(hist, off, cursor);
  k_xw<<<4000, 256, 0, stream>>>(x, lin_wT, deg, xw, dis);
  k_scatter<<<500, 256, 0, stream>>>(ei, batch, dis, cursor, bucket);
  k_gather<<<dim3(8, GB), 256, 0, stream>>>(bucket, off, xw, gsum);

  // ---- CNN phase (aliases xw region; xw is dead after k_gather) ----
  for (int b0 = 0; b0 < GB; b0 += CB) {
    k_conv1<<<dim3(8, CB), 256, 0, stream>>>(target, w1T, b1, h1, b0);
    k_conv2<<<dim3(8, CB), 256, 0, stream>>>(h1, w2T, b2, h2T);
    k_conv3<<<dim3(8, CB), 256, 0, stream>>>(h2T, w3t, b3, pooledT, b0);
  }

  // ---- head ----
  k_fc<<<384, 256, 0, stream>>>(pooledT, fcw, fcb, tgtT, 1024, 768, 1, nullptr);
  k_z0<<<512, 256, 0, stream>>>(gsum, start, lin_b, tgtT, z0T);
  k_fc<<<512, 256, 0, stream>>>(z0T, m1w, m1b, z1T, 1024, 1024, 1, nullptr);
  k_fc<<<512, 256, 0, stream>>>(z1T, m2w, m2b, z2T, 1024, 1024, 1, nullptr);
  k_fc<<<256, 256, 0, stream>>>(z2T, m3w, m3b, z3T, 1024, 512, 1, nullptr);
  k_fc<<<1, 256, 0, stream>>>(z3T, m4w, m4b, nullptr, 512, 1, 0, (float*)d_out);
}